// Round 1
// baseline (308.066 us; speedup 1.0000x reference)
//
#include <hip/hip_runtime.h>
#include <cstdint>

#define NAG 25
#define NS 32
#define EHH 3200      // EHH_HID
#define KDIM 800      // N_AGENT*N_S
#define BATCH 2048
#define NEDGE 300
#define NPAD 384      // 300 padded to 3x128
#define KSPLIT 4

typedef _Float16 half8 __attribute__((ext_vector_type(8)));
typedef float f32x4 __attribute__((ext_vector_type(4)));

__device__ __forceinline__ float leaky(float x) { return x >= 0.f ? x : 0.01f * x; }

// ---------------- batch-norm stats: mean/var over batch per feature ----------------
__global__ void stats_kernel(const float* __restrict__ states,
                             float* __restrict__ mu, float* __restrict__ rs) {
    int a = blockIdx.x;
    int s = threadIdx.x & 31, ty = threadIdx.x >> 5;   // 32 features x 8 rows
    const float* base = states + (size_t)a * BATCH * NS + s;
    float sum = 0.f, sq = 0.f;
    for (int b = ty; b < BATCH; b += 8) {
        float v = base[(size_t)b * NS];
        sum += v; sq += v * v;
    }
    __shared__ float ls[8][32], lq[8][32];
    ls[ty][s] = sum; lq[ty][s] = sq;
    __syncthreads();
    if (ty == 0) {
        for (int i = 1; i < 8; ++i) { sum += ls[i][s]; sq += lq[i][s]; }
        float m = sum * (1.f / BATCH);
        float var = sq * (1.f / BATCH) - m * m;
        mu[a * 32 + s] = m;
        rs[a * 32 + s] = rsqrtf(var + 1e-5f);
    }
}

// ---------------- build normalized A (2048 x 800) fp16 ----------------
__global__ void norma_kernel(const float* __restrict__ states, const float* __restrict__ mu,
                             const float* __restrict__ rs, _Float16* __restrict__ A) {
    int t = blockIdx.x * 256 + threadIdx.x;   // t = b*800 + f
    int b = t / KDIM;
    int f = t - b * KDIM;
    int a = f >> 5, s = f & 31;
    float v = states[((size_t)a * BATCH + b) * NS + s];
    A[t] = (_Float16)((v - mu[f]) * rs[f]);
}

// ---------------- transpose+cast ehh_w (800x3200 f32) -> WbT (3200x800 fp16) ----------------
__global__ void wtrans_kernel(const float* __restrict__ w, _Float16* __restrict__ wt) {
    __shared__ float tile[32][33];
    int n0 = blockIdx.x * 32, k0 = blockIdx.y * 32;
    int x = threadIdx.x, y = threadIdx.y;
    for (int i = y; i < 32; i += 8)
        tile[i][x] = w[(size_t)(k0 + i) * EHH + n0 + x];
    __syncthreads();
    for (int i = y; i < 32; i += 8)
        wt[(size_t)(n0 + i) * KDIM + k0 + x] = (_Float16)tile[x][i];
}

// ---------------- attention: self + sequential scatter (numpy last-writer-wins order) ----------------
__global__ void att_kernel(const float* __restrict__ anova, const int* __restrict__ adj,
                           float* __restrict__ att) {
    __shared__ float vals[NEDGE * NAG];   // 30 KB
    __shared__ int d1[NEDGE], d3[NEDGE];
    int tid = threadIdx.x;
    for (int i = tid; i < NEDGE * NAG; i += 256) {
        int e = i / NAG, a = i - e * NAG;
        int src = adj[e * 4 + 0];
        vals[i] = anova[(size_t)(EHH + src) * NAG + a];
    }
    for (int e = tid; e < NEDGE; e += 256) { d1[e] = adj[e * 4 + 1]; d3[e] = adj[e * 4 + 3]; }
    const int TOT = EHH * NAG;
    for (int i = tid; i < TOT; i += 256) att[i] = 0.f;
    __syncthreads();
    if (tid < NAG) {   // lane 'tid' owns agent column tid; serial over edges = numpy order
        for (int e = 0; e < NEDGE; ++e) att[d1[e] * NAG + tid] = vals[e * NAG + tid];
        for (int e = 0; e < NEDGE; ++e) att[d3[e] * NAG + tid] = vals[e * NAG + tid];
    }
    __syncthreads();
    for (int i = tid; i < TOT; i += 256) att[i] += anova[i];
}

// ---------------- fused weight: W2dT[n=a*12+k][h] = att[h,a]*w1[a,h,k]  (NPAD x 3200 fp16) ----------------
__global__ void w2d_kernel(const float* __restrict__ att, const float* __restrict__ w1,
                           _Float16* __restrict__ w2dt) {
    int h = blockIdx.x * 128 + threadIdx.x;
    int n = blockIdx.y;
    float v = 0.f;
    if (n < 300) {
        int a = n / 12, kk = n - a * 12;
        v = att[h * NAG + a] * w1[((size_t)a * EHH + h) * 12 + kk];
    }
    w2dt[(size_t)n * EHH + h] = (_Float16)v;
}

// ---------------- 128x128 MFMA GEMM, C = A(MxK) * B^T(NxK), both fp16 row-major k-contiguous ----------------
__device__ __forceinline__ void async16(const void* g, void* l) {
    __builtin_amdgcn_global_load_lds(
        (const __attribute__((address_space(1))) void*)(uintptr_t)g,
        (__attribute__((address_space(3))) void*)(unsigned)(uintptr_t)l, 16, 0, 0);
}

template <bool LEAKY_F16_OUT>
__global__ __launch_bounds__(256)
void gemm_bt(const _Float16* __restrict__ A, const _Float16* __restrict__ B,
             _Float16* __restrict__ Ch, float* __restrict__ Cf,
             int Ktot, int ldc, int kPerSplit, int slabStride) {
    __shared__ __attribute__((aligned(16))) _Float16 As[128 * 32];
    __shared__ __attribute__((aligned(16))) _Float16 Bs[128 * 32];
    const int tid = threadIdx.x;
    const int lane = tid & 63;
    const int wave = tid >> 6;            // 4 waves, 2x2
    const int wm = (wave >> 1) << 6;
    const int wn = (wave & 1) << 6;
    const int m0 = blockIdx.x << 7;
    const int n0 = blockIdx.y << 7;
    const int k0 = blockIdx.z * kPerSplit;
    const int nk = kPerSplit >> 5;

    // staging: each wave covers 16 rows per issue (64 lanes * 16B = 16 rows * 64B)
    const int srow = lane >> 2;
    const int scol = (lane & 3) << 3;
    const _Float16* gA0 = A + (size_t)(m0 + wave * 16 + srow) * Ktot + k0 + scol;
    const _Float16* gA1 = gA0 + (size_t)64 * Ktot;
    const _Float16* gB0 = B + (size_t)(n0 + wave * 16 + srow) * Ktot + k0 + scol;
    const _Float16* gB1 = gB0 + (size_t)64 * Ktot;
    _Float16* lA0 = As + wave * 512;
    _Float16* lA1 = As + 2048 + wave * 512;
    _Float16* lB0 = Bs + wave * 512;
    _Float16* lB1 = Bs + 2048 + wave * 512;

    f32x4 acc[4][4];
    const f32x4 zero = {0.f, 0.f, 0.f, 0.f};
#pragma unroll
    for (int i = 0; i < 4; ++i)
#pragma unroll
        for (int j = 0; j < 4; ++j) acc[i][j] = zero;

    const int fr = lane & 15;             // m (A) / n (B) within 16-tile
    const int q8 = (lane >> 4) << 3;      // k offset of this lane's 8 elements

    for (int kt = 0; kt < nk; ++kt) {
        const int ko = kt << 5;
        __syncthreads();
        async16(gA0 + ko, lA0);
        async16(gA1 + ko, lA1);
        async16(gB0 + ko, lB0);
        async16(gB1 + ko, lB1);
        __syncthreads();   // drains vmcnt before barrier (m97 structure)

        half8 av[4], bv[4];
#pragma unroll
        for (int i = 0; i < 4; ++i)
            av[i] = *(const half8*)(As + (wm + i * 16 + fr) * 32 + q8);
#pragma unroll
        for (int j = 0; j < 4; ++j)
            bv[j] = *(const half8*)(Bs + (wn + j * 16 + fr) * 32 + q8);
#pragma unroll
        for (int i = 0; i < 4; ++i)
#pragma unroll
            for (int j = 0; j < 4; ++j)
                acc[i][j] = __builtin_amdgcn_mfma_f32_16x16x32_f16(av[i], bv[j], acc[i][j], 0, 0, 0);
    }

    // C/D layout: col = lane&15, row = (lane>>4)*4 + reg   [m89-verified]
    const int r0 = (lane >> 4) << 2;
    if (LEAKY_F16_OUT) {
#pragma unroll
        for (int i = 0; i < 4; ++i)
#pragma unroll
            for (int j = 0; j < 4; ++j)
#pragma unroll
                for (int r = 0; r < 4; ++r) {
                    int row = m0 + wm + i * 16 + r0 + r;
                    int col = n0 + wn + j * 16 + fr;
                    Ch[(size_t)row * ldc + col] = (_Float16)leaky(acc[i][j][r]);
                }
    } else {
        float* C = Cf + (size_t)blockIdx.z * slabStride;
#pragma unroll
        for (int i = 0; i < 4; ++i)
#pragma unroll
            for (int j = 0; j < 4; ++j)
#pragma unroll
                for (int r = 0; r < 4; ++r) {
                    int row = m0 + wm + i * 16 + r0 + r;
                    int col = n0 + wn + j * 16 + fr;
                    C[(size_t)row * ldc + col] = acc[i][j][r];
                }
    }
}

// ---------------- tail: reduce split-K, bias+leaky, 12x12, 12x4, action gather ----------------
__global__ void tail_kernel(const float* __restrict__ Hp, const float* __restrict__ b1,
                            const float* __restrict__ w2, const float* __restrict__ b2,
                            const float* __restrict__ w3, const float* __restrict__ b3,
                            const int* __restrict__ act, float* __restrict__ out) {
    int t = blockIdx.x * 256 + threadIdx.x;   // t = a*2048 + b
    int b = t & (BATCH - 1);
    int a = t >> 11;
    const float* hp = Hp + (size_t)b * NPAD + a * 12;
    float h1[12];
#pragma unroll
    for (int k = 0; k < 12; ++k) {
        float s = b1[a * 12 + k];
#pragma unroll
        for (int ks = 0; ks < KSPLIT; ++ks) s += hp[(size_t)ks * BATCH * NPAD + k];
        h1[k] = leaky(s);
    }
    float h2[12];
#pragma unroll
    for (int j = 0; j < 12; ++j) {
        float s = b2[a * 12 + j];
#pragma unroll
        for (int k = 0; k < 12; ++k) s += h1[k] * w2[(a * 12 + k) * 12 + j];
        h2[j] = leaky(s);
    }
    int c = act[t];
    float q = b3[a * 4 + c];
#pragma unroll
    for (int j = 0; j < 12; ++j) q += h2[j] * w3[(a * 12 + j) * 4 + c];
    out[t] = q;
}

extern "C" void kernel_launch(void* const* d_in, const int* in_sizes, int n_in,
                              void* d_out, int out_size, void* d_ws, size_t ws_size,
                              hipStream_t stream) {
    (void)in_sizes; (void)n_in; (void)out_size; (void)ws_size;
    const float* states = (const float*)d_in[0];
    const float* ehh_w  = (const float*)d_in[1];
    const float* anova  = (const float*)d_in[2];
    const float* w1     = (const float*)d_in[3];
    const float* b1     = (const float*)d_in[4];
    const float* w2     = (const float*)d_in[5];
    const float* b2     = (const float*)d_in[6];
    const float* w3     = (const float*)d_in[7];
    const float* b3     = (const float*)d_in[8];
    const int* actions  = (const int*)d_in[9];
    const int* adj      = (const int*)d_in[10];
    float* out = (float*)d_out;

    char* ws = (char*)d_ws;
    float*     mu   = (float*)    (ws + 0);            // 800 f32
    float*     rs   = (float*)    (ws + 4096);         // 800 f32
    float*     att  = (float*)    (ws + 8192);         // 3200*25 f32
    _Float16*  Abf  = (_Float16*) (ws + 331776);       // 2048*800
    _Float16*  WbT  = (_Float16*) (ws + 3608576);      // 3200*800
    _Float16*  W2dT = (_Float16*) (ws + 8728576);      // 384*3200
    _Float16*  emb  = (_Float16*) (ws + 11186176);     // 2048*3200
    float*     Hp   = (float*)    (ws + 24293376);     // KSPLIT*2048*384 f32

    stats_kernel<<<25, 256, 0, stream>>>(states, mu, rs);
    norma_kernel<<<(BATCH * KDIM) / 256, 256, 0, stream>>>(states, mu, rs, Abf);
    wtrans_kernel<<<dim3(EHH / 32, KDIM / 32), dim3(32, 8), 0, stream>>>(ehh_w, WbT);
    att_kernel<<<1, 256, 0, stream>>>(anova, adj, att);
    w2d_kernel<<<dim3(EHH / 128, NPAD), 128, 0, stream>>>(att, w1, W2dT);
    // GEMM1: emb = leaky(A @ WbT^T)   M=2048 N=3200 K=800
    gemm_bt<true><<<dim3(16, 25, 1), 256, 0, stream>>>(Abf, WbT, emb, nullptr, KDIM, EHH, KDIM, 0);
    // GEMM2: Hp = emb @ W2dT^T (split-K x4)   M=2048 N=384 K=3200
    gemm_bt<false><<<dim3(16, 3, KSPLIT), 256, 0, stream>>>(emb, W2dT, nullptr, Hp, EHH, NPAD,
                                                            EHH / KSPLIT, BATCH * NPAD);
    tail_kernel<<<(BATCH * NAG) / 256, 256, 0, stream>>>(Hp, b1, w2, b2, w3, b3, actions, out);
}

// Round 2
// 165.104 us; speedup vs baseline: 1.8659x; 1.8659x over previous
//
#include <hip/hip_runtime.h>
#include <cstdint>

#define NAG 25
#define NS 32
#define EHH 3200      // EHH_HID
#define KDIM 800      // N_AGENT*N_S
#define BATCH 2048
#define NEDGE 300
#define NPAD 384      // 300 padded to 3x128
#define KSPLIT 4

typedef _Float16 half8 __attribute__((ext_vector_type(8)));
typedef float f32x4 __attribute__((ext_vector_type(4)));

__device__ __forceinline__ float leaky(float x) { return x >= 0.f ? x : 0.01f * x; }

// ---------------- init: zero stats accumulators, winner = -1 ----------------
__global__ void init_kernel(float* __restrict__ acc, int* __restrict__ winner) {
    int t = blockIdx.x * 256 + threadIdx.x;
    if (t < 1600) acc[t] = 0.f;
    if (t < EHH) winner[t] = -1;
}

// ---------------- batch-norm partial stats: (25 agents x 16 chunks) blocks ----------------
__global__ void stats_part(const float* __restrict__ states, float* __restrict__ acc) {
    int a = blockIdx.x;            // agent
    int chunk = blockIdx.y;        // 128 batch rows each
    int s = threadIdx.x & 31, ty = threadIdx.x >> 5;
    const float* base = states + ((size_t)a * BATCH + chunk * 128) * NS + s;
    float sum = 0.f, sq = 0.f;
    for (int b = ty; b < 128; b += 8) {
        float v = base[(size_t)b * NS];
        sum += v; sq += v * v;
    }
    __shared__ float ls[8][32], lq[8][32];
    ls[ty][s] = sum; lq[ty][s] = sq;
    __syncthreads();
    if (ty == 0) {
#pragma unroll
        for (int i = 1; i < 8; ++i) { sum += ls[i][s]; sq += lq[i][s]; }
        atomicAdd(&acc[a * 32 + s], sum);
        atomicAdd(&acc[800 + a * 32 + s], sq);
    }
}

// ---------------- normalize: A (2048 x 800) fp16; finalize of stats folded in ----------------
__global__ void norma_kernel(const float* __restrict__ states, const float* __restrict__ acc,
                             _Float16* __restrict__ A) {
    int t = blockIdx.x * 256 + threadIdx.x;   // t = b*800 + f
    int b = t / KDIM;
    int f = t - b * KDIM;
    int a = f >> 5, s = f & 31;
    float m = acc[f] * (1.f / BATCH);
    float var = acc[800 + f] * (1.f / BATCH) - m * m;
    float rs = rsqrtf(var + 1e-5f);
    float v = states[((size_t)a * BATCH + b) * NS + s];
    A[t] = (_Float16)((v - m) * rs);
}

// ---------------- transpose+cast ehh_w (800x3200 f32) -> WbT (3200x800 fp16) ----------------
__global__ void wtrans_kernel(const float* __restrict__ w, _Float16* __restrict__ wt) {
    __shared__ float tile[32][33];
    int n0 = blockIdx.x * 32, k0 = blockIdx.y * 32;
    int x = threadIdx.x, y = threadIdx.y;
    for (int i = y; i < 32; i += 8)
        tile[i][x] = w[(size_t)(k0 + i) * EHH + n0 + x];
    __syncthreads();
    for (int i = y; i < 32; i += 8)
        wt[(size_t)(n0 + i) * KDIM + k0 + x] = (_Float16)tile[x][i];
}

// ---------------- scatter winner: last sequential writer == max priority ----------------
// pass1 (adj[:,1]) edge e -> prio e; pass2 (adj[:,3]) edge e -> prio NEDGE+e.
__global__ void scatter_win(const int* __restrict__ adj, int* __restrict__ winner) {
    int e = blockIdx.x * 256 + threadIdx.x;
    if (e < 2 * NEDGE) {
        int pass = e >= NEDGE;
        int ee = pass ? e - NEDGE : e;
        int dest = adj[ee * 4 + (pass ? 3 : 1)];
        atomicMax(&winner[dest], e);
    }
}

// ---------------- fused weight: W2dT[n=a*12+k][h] = att(h,a)*w1[a,h,k]  (NPAD x 3200 fp16) ----------------
__global__ void w2d_kernel(const float* __restrict__ anova, const int* __restrict__ adj,
                           const int* __restrict__ winner, const float* __restrict__ w1,
                           _Float16* __restrict__ w2dt) {
    int h = blockIdx.x * 128 + threadIdx.x;
    int n = blockIdx.y;
    float v = 0.f;
    if (n < 300) {
        int a = n / 12, kk = n - a * 12;
        float att = anova[(size_t)h * NAG + a];
        int w = winner[h];
        if (w >= 0) {
            int ee = w >= NEDGE ? w - NEDGE : w;
            int src = adj[ee * 4 + 0];
            att += anova[(size_t)(EHH + src) * NAG + a];
        }
        v = att * w1[((size_t)a * EHH + h) * 12 + kk];
    }
    w2dt[(size_t)n * EHH + h] = (_Float16)v;
}

// ---------------- 128x128 MFMA GEMM, C = A(MxK) * B^T(NxK), both fp16 row-major k-contiguous ----------------
__device__ __forceinline__ void async16(const void* g, void* l) {
    __builtin_amdgcn_global_load_lds(
        (const __attribute__((address_space(1))) void*)(uintptr_t)g,
        (__attribute__((address_space(3))) void*)(unsigned)(uintptr_t)l, 16, 0, 0);
}

template <bool LEAKY_F16_OUT>
__global__ __launch_bounds__(256)
void gemm_bt(const _Float16* __restrict__ A, const _Float16* __restrict__ B,
             _Float16* __restrict__ Ch, float* __restrict__ Cf,
             int Ktot, int ldc, int kPerSplit, int slabStride) {
    __shared__ __attribute__((aligned(16))) _Float16 As[128 * 32];
    __shared__ __attribute__((aligned(16))) _Float16 Bs[128 * 32];
    const int tid = threadIdx.x;
    const int lane = tid & 63;
    const int wave = tid >> 6;            // 4 waves, 2x2
    const int wm = (wave >> 1) << 6;
    const int wn = (wave & 1) << 6;
    const int m0 = blockIdx.x << 7;
    const int n0 = blockIdx.y << 7;
    const int k0 = blockIdx.z * kPerSplit;
    const int nk = kPerSplit >> 5;

    // staging: each wave covers 16 rows per issue (64 lanes * 16B = 16 rows * 64B)
    const int srow = lane >> 2;
    const int scol = (lane & 3) << 3;
    const _Float16* gA0 = A + (size_t)(m0 + wave * 16 + srow) * Ktot + k0 + scol;
    const _Float16* gA1 = gA0 + (size_t)64 * Ktot;
    const _Float16* gB0 = B + (size_t)(n0 + wave * 16 + srow) * Ktot + k0 + scol;
    const _Float16* gB1 = gB0 + (size_t)64 * Ktot;
    _Float16* lA0 = As + wave * 512;
    _Float16* lA1 = As + 2048 + wave * 512;
    _Float16* lB0 = Bs + wave * 512;
    _Float16* lB1 = Bs + 2048 + wave * 512;

    f32x4 acc[4][4];
    const f32x4 zero = {0.f, 0.f, 0.f, 0.f};
#pragma unroll
    for (int i = 0; i < 4; ++i)
#pragma unroll
        for (int j = 0; j < 4; ++j) acc[i][j] = zero;

    const int fr = lane & 15;             // m (A) / n (B) within 16-tile
    const int q8 = (lane >> 4) << 3;      // k offset of this lane's 8 elements

    for (int kt = 0; kt < nk; ++kt) {
        const int ko = kt << 5;
        __syncthreads();
        async16(gA0 + ko, lA0);
        async16(gA1 + ko, lA1);
        async16(gB0 + ko, lB0);
        async16(gB1 + ko, lB1);
        __syncthreads();   // drains vmcnt before barrier (m97 structure)

        half8 av[4], bv[4];
#pragma unroll
        for (int i = 0; i < 4; ++i)
            av[i] = *(const half8*)(As + (wm + i * 16 + fr) * 32 + q8);
#pragma unroll
        for (int j = 0; j < 4; ++j)
            bv[j] = *(const half8*)(Bs + (wn + j * 16 + fr) * 32 + q8);
#pragma unroll
        for (int i = 0; i < 4; ++i)
#pragma unroll
            for (int j = 0; j < 4; ++j)
                acc[i][j] = __builtin_amdgcn_mfma_f32_16x16x32_f16(av[i], bv[j], acc[i][j], 0, 0, 0);
    }

    // C/D layout: col = lane&15, row = (lane>>4)*4 + reg   [m89-verified]
    const int r0 = (lane >> 4) << 2;
    if (LEAKY_F16_OUT) {
#pragma unroll
        for (int i = 0; i < 4; ++i)
#pragma unroll
            for (int j = 0; j < 4; ++j)
#pragma unroll
                for (int r = 0; r < 4; ++r) {
                    int row = m0 + wm + i * 16 + r0 + r;
                    int col = n0 + wn + j * 16 + fr;
                    Ch[(size_t)row * ldc + col] = (_Float16)leaky(acc[i][j][r]);
                }
    } else {
        float* C = Cf + (size_t)blockIdx.z * slabStride;
#pragma unroll
        for (int i = 0; i < 4; ++i)
#pragma unroll
            for (int j = 0; j < 4; ++j)
#pragma unroll
                for (int r = 0; r < 4; ++r) {
                    int row = m0 + wm + i * 16 + r0 + r;
                    int col = n0 + wn + j * 16 + fr;
                    C[(size_t)row * ldc + col] = acc[i][j][r];
                }
    }
}

// ---------------- tail: reduce split-K, bias+leaky, 12x12, 12x4, action gather ----------------
__global__ void tail_kernel(const float* __restrict__ Hp, const float* __restrict__ b1,
                            const float* __restrict__ w2, const float* __restrict__ b2,
                            const float* __restrict__ w3, const float* __restrict__ b3,
                            const int* __restrict__ act, float* __restrict__ out) {
    int t = blockIdx.x * 256 + threadIdx.x;   // t = a*2048 + b
    int b = t & (BATCH - 1);
    int a = t >> 11;
    const float* hp = Hp + (size_t)b * NPAD + a * 12;
    float h1[12];
#pragma unroll
    for (int k = 0; k < 12; ++k) {
        float s = b1[a * 12 + k];
#pragma unroll
        for (int ks = 0; ks < KSPLIT; ++ks) s += hp[(size_t)ks * BATCH * NPAD + k];
        h1[k] = leaky(s);
    }
    float h2[12];
#pragma unroll
    for (int j = 0; j < 12; ++j) {
        float s = b2[a * 12 + j];
#pragma unroll
        for (int k = 0; k < 12; ++k) s += h1[k] * w2[(a * 12 + k) * 12 + j];
        h2[j] = leaky(s);
    }
    int c = act[t];
    float q = b3[a * 4 + c];
#pragma unroll
    for (int j = 0; j < 12; ++j) q += h2[j] * w3[(a * 12 + j) * 4 + c];
    out[t] = q;
}

extern "C" void kernel_launch(void* const* d_in, const int* in_sizes, int n_in,
                              void* d_out, int out_size, void* d_ws, size_t ws_size,
                              hipStream_t stream) {
    (void)in_sizes; (void)n_in; (void)out_size; (void)ws_size;
    const float* states = (const float*)d_in[0];
    const float* ehh_w  = (const float*)d_in[1];
    const float* anova  = (const float*)d_in[2];
    const float* w1     = (const float*)d_in[3];
    const float* b1     = (const float*)d_in[4];
    const float* w2     = (const float*)d_in[5];
    const float* b2     = (const float*)d_in[6];
    const float* w3     = (const float*)d_in[7];
    const float* b3     = (const float*)d_in[8];
    const int* actions  = (const int*)d_in[9];
    const int* adj      = (const int*)d_in[10];
    float* out = (float*)d_out;

    char* ws = (char*)d_ws;
    float*     acc    = (float*)    (ws + 0);            // 1600 f32 (sum, sumsq)
    int*       winner = (int*)      (ws + 8192);         // 3200 i32
    _Float16*  Abf    = (_Float16*) (ws + 32768);        // 2048*800 fp16
    _Float16*  WbT    = (_Float16*) (ws + 3311616);      // 3200*800 fp16
    _Float16*  W2dT   = (_Float16*) (ws + 8433664);      // 384*3200 fp16
    _Float16*  emb    = (_Float16*) (ws + 10893312);     // 2048*3200 fp16
    float*     Hp     = (float*)    (ws + 24002560);     // KSPLIT*2048*384 f32  (end ~36.6 MB)

    init_kernel<<<13, 256, 0, stream>>>(acc, winner);
    stats_part<<<dim3(25, 16), 256, 0, stream>>>(states, acc);
    norma_kernel<<<(BATCH * KDIM) / 256, 256, 0, stream>>>(states, acc, Abf);
    wtrans_kernel<<<dim3(EHH / 32, KDIM / 32), dim3(32, 8), 0, stream>>>(ehh_w, WbT);
    scatter_win<<<3, 256, 0, stream>>>(adj, winner);
    w2d_kernel<<<dim3(EHH / 128, NPAD), 128, 0, stream>>>(anova, adj, winner, w1, W2dT);
    // GEMM1: emb = leaky(A @ WbT^T)   M=2048 N=3200 K=800
    gemm_bt<true><<<dim3(16, 25, 1), 256, 0, stream>>>(Abf, WbT, emb, nullptr, KDIM, EHH, KDIM, 0);
    // GEMM2: Hp = emb @ W2dT^T (split-K x4)   M=2048 N=384 K=3200
    gemm_bt<false><<<dim3(16, 3, KSPLIT), 256, 0, stream>>>(emb, W2dT, nullptr, Hp, EHH, NPAD,
                                                            EHH / KSPLIT, BATCH * NPAD);
    tail_kernel<<<(BATCH * NAG) / 256, 256, 0, stream>>>(Hp, b1, w2, b2, w3, b3, actions, out);
}

// Round 3
// 143.912 us; speedup vs baseline: 2.1407x; 1.1473x over previous
//
#include <hip/hip_runtime.h>
#include <cstdint>

#define NAG 25
#define NS 32
#define EHH 3200      // EHH_HID
#define KDIM 800      // N_AGENT*N_S
#define BATCH 2048
#define NEDGE 300
#define NPAD 384      // 300 padded to 3x128
#define KSPLIT 5

typedef _Float16 half8 __attribute__((ext_vector_type(8)));
typedef float f32x4 __attribute__((ext_vector_type(4)));

__device__ __forceinline__ float leaky(float x) { return x >= 0.f ? x : 0.01f * x; }

// ---------------- init: zero stats accumulators, winner = -1 ----------------
__global__ void init_kernel(float* __restrict__ acc, int* __restrict__ winner) {
    int t = blockIdx.x * 256 + threadIdx.x;
    if (t < 1600) acc[t] = 0.f;
    if (t < EHH) winner[t] = -1;
}

// ---------------- batch-norm partial stats: (25 agents x 16 chunks) blocks ----------------
__global__ void stats_part(const float* __restrict__ states, float* __restrict__ acc) {
    int a = blockIdx.x;            // agent
    int chunk = blockIdx.y;        // 128 batch rows each
    int s = threadIdx.x & 31, ty = threadIdx.x >> 5;
    const float* base = states + ((size_t)a * BATCH + chunk * 128) * NS + s;
    float sum = 0.f, sq = 0.f;
    for (int b = ty; b < 128; b += 8) {
        float v = base[(size_t)b * NS];
        sum += v; sq += v * v;
    }
    __shared__ float ls[8][32], lq[8][32];
    ls[ty][s] = sum; lq[ty][s] = sq;
    __syncthreads();
    if (ty == 0) {
#pragma unroll
        for (int i = 1; i < 8; ++i) { sum += ls[i][s]; sq += lq[i][s]; }
        atomicAdd(&acc[a * 32 + s], sum);
        atomicAdd(&acc[800 + a * 32 + s], sq);
    }
}

// ---------------- fused prep: normalize A | transpose ehh_w | edge scatter ----------------
// blocks [0,6400): norma; [6400,8900): wtrans; [8900,8903): scatter_win
__global__ void prep_kernel(const float* __restrict__ states, const float* __restrict__ acc,
                            const float* __restrict__ ehh_w, const int* __restrict__ adj,
                            int* __restrict__ winner,
                            _Float16* __restrict__ A, _Float16* __restrict__ wt) {
    __shared__ float tile[32][33];
    int bi = blockIdx.x;
    if (bi < 6400) {
        int t = bi * 256 + threadIdx.x;   // t = b*800 + f
        int b = t / KDIM;
        int f = t - b * KDIM;
        int a = f >> 5, s = f & 31;
        float m = acc[f] * (1.f / BATCH);
        float var = acc[800 + f] * (1.f / BATCH) - m * m;
        float rs = rsqrtf(var + 1e-5f);
        float v = states[((size_t)a * BATCH + b) * NS + s];
        A[t] = (_Float16)((v - m) * rs);
    } else if (bi < 8900) {
        int bb = bi - 6400;
        int n0 = (bb % 100) * 32, k0 = (bb / 100) * 32;
        int x = threadIdx.x & 31, y = threadIdx.x >> 5;
        for (int i = y; i < 32; i += 8)
            tile[i][x] = ehh_w[(size_t)(k0 + i) * EHH + n0 + x];
        __syncthreads();
        for (int i = y; i < 32; i += 8)
            wt[(size_t)(n0 + i) * KDIM + k0 + x] = (_Float16)tile[x][i];
    } else {
        // last sequential writer == max priority: pass1 edge e -> prio e, pass2 -> NEDGE+e
        int e = (bi - 8900) * 256 + threadIdx.x;
        if (e < 2 * NEDGE) {
            int pass = e >= NEDGE;
            int ee = pass ? e - NEDGE : e;
            int dest = adj[ee * 4 + (pass ? 3 : 1)];
            atomicMax(&winner[dest], e);
        }
    }
}

// ---------------- fused weight: W2dT[n=a*12+k][h] = att(h,a)*w1[a,h,k]  (NPAD x 3200 fp16) ----------------
// one thread per (a,h): contiguous 48B w1 read, 12 coalesced column store streams
__global__ void w2d_kernel(const float* __restrict__ anova, const int* __restrict__ adj,
                           const int* __restrict__ winner, const float* __restrict__ w1,
                           _Float16* __restrict__ w2dt) {
    if (blockIdx.x < 313) {
        int t = blockIdx.x * 256 + threadIdx.x;   // t = a*3200 + h
        if (t < NAG * EHH) {
            int a = t / EHH;
            int h = t - a * EHH;
            float att = anova[(size_t)h * NAG + a];
            int w = winner[h];
            if (w >= 0) {
                int ee = w >= NEDGE ? w - NEDGE : w;
                att += anova[(size_t)(EHH + adj[ee * 4]) * NAG + a];
            }
            const float* wp = w1 + ((size_t)a * EHH + h) * 12;
#pragma unroll
            for (int kk = 0; kk < 12; ++kk)
                w2dt[(size_t)(a * 12 + kk) * EHH + h] = (_Float16)(att * wp[kk]);
        }
    } else {
        // pad rows 300..383 -> zero, 16B per thread
        int p = (blockIdx.x - 313) * 256 + threadIdx.x;
        if (p < (NPAD - 300) * EHH / 8) {
            half8 z = {0, 0, 0, 0, 0, 0, 0, 0};
            ((half8*)(w2dt + (size_t)300 * EHH))[p] = z;
        }
    }
}

// ---------------- 128x128 MFMA GEMM, C = A(MxK) * B^T(NxK), fp16 k-contiguous ----------------
// Double-buffered LDS: one barrier per K-iteration; loads for tile k+1 fly during MFMA of tile k.
__device__ __forceinline__ void async16(const void* g, void* l) {
    __builtin_amdgcn_global_load_lds(
        (const __attribute__((address_space(1))) void*)(uintptr_t)g,
        (__attribute__((address_space(3))) void*)(unsigned)(uintptr_t)l, 16, 0, 0);
}

template <bool LEAKY_F16_OUT>
__global__ __launch_bounds__(256)
void gemm_bt(const _Float16* __restrict__ A, const _Float16* __restrict__ B,
             _Float16* __restrict__ Ch, float* __restrict__ Cf,
             int Ktot, int ldc, int kPerSplit, int slabStride) {
    __shared__ __attribute__((aligned(16))) _Float16 As[2][128 * 32];
    __shared__ __attribute__((aligned(16))) _Float16 Bs[2][128 * 32];
    const int tid = threadIdx.x;
    const int lane = tid & 63;
    const int wave = tid >> 6;            // 4 waves, 2x2
    const int wm = (wave >> 1) << 6;
    const int wn = (wave & 1) << 6;
    const int m0 = blockIdx.x << 7;
    const int n0 = blockIdx.y << 7;
    const int k0 = blockIdx.z * kPerSplit;
    const int nk = kPerSplit >> 5;

    // staging: each wave covers 16 rows per issue (64 lanes * 16B = 16 rows * 64B)
    const int srow = lane >> 2;
    const int scol = (lane & 3) << 3;
    const _Float16* gA0 = A + (size_t)(m0 + wave * 16 + srow) * Ktot + k0 + scol;
    const _Float16* gA1 = gA0 + (size_t)64 * Ktot;
    const _Float16* gB0 = B + (size_t)(n0 + wave * 16 + srow) * Ktot + k0 + scol;
    const _Float16* gB1 = gB0 + (size_t)64 * Ktot;
    const int lofs = wave * 512;

    f32x4 acc[4][4];
    const f32x4 zero = {0.f, 0.f, 0.f, 0.f};
#pragma unroll
    for (int i = 0; i < 4; ++i)
#pragma unroll
        for (int j = 0; j < 4; ++j) acc[i][j] = zero;

    const int fr = lane & 15;             // m (A) / n (B) within 16-tile
    const int q8 = (lane >> 4) << 3;      // k offset of this lane's 8 elements

    // prologue: stage tile 0 into buffer 0
    async16(gA0, As[0] + lofs);
    async16(gA1, As[0] + 2048 + lofs);
    async16(gB0, Bs[0] + lofs);
    async16(gB1, Bs[0] + 2048 + lofs);

    for (int kt = 0; kt < nk; ++kt) {
        const int cur = kt & 1;
        __syncthreads();   // drains vmcnt(0): buf[cur] staged; all readers of buf[cur^1] done
        if (kt + 1 < nk) {
            const int ko = (kt + 1) << 5;
            const int nxt = cur ^ 1;
            async16(gA0 + ko, As[nxt] + lofs);
            async16(gA1 + ko, As[nxt] + 2048 + lofs);
            async16(gB0 + ko, Bs[nxt] + lofs);
            async16(gB1 + ko, Bs[nxt] + 2048 + lofs);
        }
        half8 av[4], bv[4];
#pragma unroll
        for (int i = 0; i < 4; ++i)
            av[i] = *(const half8*)(As[cur] + (wm + i * 16 + fr) * 32 + q8);
#pragma unroll
        for (int j = 0; j < 4; ++j)
            bv[j] = *(const half8*)(Bs[cur] + (wn + j * 16 + fr) * 32 + q8);
#pragma unroll
        for (int i = 0; i < 4; ++i)
#pragma unroll
            for (int j = 0; j < 4; ++j)
                acc[i][j] = __builtin_amdgcn_mfma_f32_16x16x32_f16(av[i], bv[j], acc[i][j], 0, 0, 0);
    }

    // C/D layout: col = lane&15, row = (lane>>4)*4 + reg   [m89-verified]
    const int r0 = (lane >> 4) << 2;
    if (LEAKY_F16_OUT) {
#pragma unroll
        for (int i = 0; i < 4; ++i)
#pragma unroll
            for (int j = 0; j < 4; ++j)
#pragma unroll
                for (int r = 0; r < 4; ++r) {
                    int row = m0 + wm + i * 16 + r0 + r;
                    int col = n0 + wn + j * 16 + fr;
                    Ch[(size_t)row * ldc + col] = (_Float16)leaky(acc[i][j][r]);
                }
    } else {
        float* C = Cf + (size_t)blockIdx.z * slabStride;
#pragma unroll
        for (int i = 0; i < 4; ++i)
#pragma unroll
            for (int j = 0; j < 4; ++j)
#pragma unroll
                for (int r = 0; r < 4; ++r) {
                    int row = m0 + wm + i * 16 + r0 + r;
                    int col = n0 + wn + j * 16 + fr;
                    C[(size_t)row * ldc + col] = acc[i][j][r];
                }
    }
}

// ---------------- tail: reduce split-K, bias+leaky, 12x12, 12x4, action gather ----------------
__global__ void tail_kernel(const float* __restrict__ Hp, const float* __restrict__ b1,
                            const float* __restrict__ w2, const float* __restrict__ b2,
                            const float* __restrict__ w3, const float* __restrict__ b3,
                            const int* __restrict__ act, float* __restrict__ out) {
    int t = blockIdx.x * 256 + threadIdx.x;   // t = a*2048 + b
    int b = t & (BATCH - 1);
    int a = t >> 11;
    const float* hp = Hp + (size_t)b * NPAD + a * 12;
    float h1[12];
#pragma unroll
    for (int k = 0; k < 12; ++k) {
        float s = b1[a * 12 + k];
#pragma unroll
        for (int ks = 0; ks < KSPLIT; ++ks) s += hp[(size_t)ks * BATCH * NPAD + k];
        h1[k] = leaky(s);
    }
    float h2[12];
#pragma unroll
    for (int j = 0; j < 12; ++j) {
        float s = b2[a * 12 + j];
#pragma unroll
        for (int k = 0; k < 12; ++k) s += h1[k] * w2[(a * 12 + k) * 12 + j];
        h2[j] = leaky(s);
    }
    int c = act[t];
    float q = b3[a * 4 + c];
#pragma unroll
    for (int j = 0; j < 12; ++j) q += h2[j] * w3[(a * 12 + j) * 4 + c];
    out[t] = q;
}

extern "C" void kernel_launch(void* const* d_in, const int* in_sizes, int n_in,
                              void* d_out, int out_size, void* d_ws, size_t ws_size,
                              hipStream_t stream) {
    (void)in_sizes; (void)n_in; (void)out_size; (void)ws_size;
    const float* states = (const float*)d_in[0];
    const float* ehh_w  = (const float*)d_in[1];
    const float* anova  = (const float*)d_in[2];
    const float* w1     = (const float*)d_in[3];
    const float* b1     = (const float*)d_in[4];
    const float* w2     = (const float*)d_in[5];
    const float* b2     = (const float*)d_in[6];
    const float* w3     = (const float*)d_in[7];
    const float* b3     = (const float*)d_in[8];
    const int* actions  = (const int*)d_in[9];
    const int* adj      = (const int*)d_in[10];
    float* out = (float*)d_out;

    char* ws = (char*)d_ws;
    float*     acc    = (float*)    (ws + 0);            // 1600 f32 (sum, sumsq)
    int*       winner = (int*)      (ws + 8192);         // 3200 i32
    _Float16*  Abf    = (_Float16*) (ws + 32768);        // 2048*800 fp16
    _Float16*  WbT    = (_Float16*) (ws + 3311616);      // 3200*800 fp16
    _Float16*  W2dT   = (_Float16*) (ws + 8433664);      // 384*3200 fp16
    _Float16*  emb    = (_Float16*) (ws + 10893312);     // 2048*3200 fp16
    float*     Hp     = (float*)    (ws + 24002560);     // KSPLIT*2048*384 f32 (end ~39.7 MB)

    init_kernel<<<13, 256, 0, stream>>>(acc, winner);
    stats_part<<<dim3(25, 16), 256, 0, stream>>>(states, acc);
    prep_kernel<<<8903, 256, 0, stream>>>(states, acc, ehh_w, adj, winner, Abf, WbT);
    w2d_kernel<<<445, 256, 0, stream>>>(anova, adj, winner, w1, W2dT);
    // GEMM1: emb = leaky(A @ WbT^T)   M=2048 N=3200 K=800
    gemm_bt<true><<<dim3(16, 25, 1), 256, 0, stream>>>(Abf, WbT, emb, nullptr, KDIM, EHH, KDIM, 0);
    // GEMM2: Hp = emb @ W2dT^T (split-K x5)   M=2048 N=384 K=3200
    gemm_bt<false><<<dim3(16, 3, KSPLIT), 256, 0, stream>>>(emb, W2dT, nullptr, Hp, EHH, NPAD,
                                                            EHH / KSPLIT, BATCH * NPAD);
    tail_kernel<<<(BATCH * NAG) / 256, 256, 0, stream>>>(Hp, b1, w2, b2, w3, b3, actions, out);
}